// Round 6
// baseline (110.045 us; speedup 1.0000x reference)
//
#include <hip/hip_runtime.h>

#define BSZ 4096
#define D 1024
#define N2 8192
#define TEMPV 0.5f
// exp(x/T) = exp2(x * log2(e)/T)
#define EXPSCALE 2.8853900817779268f
#define NTB 32      // 8192 / 256 tiles per dim

typedef __attribute__((ext_vector_type(8))) short bf16x8;
typedef __attribute__((ext_vector_type(4))) float f32x4;

__device__ inline unsigned short f2bf(float x) {
  unsigned int u = __float_as_uint(x);
  u += 0x7fffu + ((u >> 16) & 1u);   // round-to-nearest-even
  return (unsigned short)(u >> 16);
}

__device__ inline void gload16(const void* g, void* l) {
  __builtin_amdgcn_global_load_lds(
      (const __attribute__((address_space(1))) void*)g,
      (__attribute__((address_space(3))) void*)l, 16, 0, 0);
}

// ---------------- Kernel A: L2-normalize rows, emit bf16 reps + pos dot ----------------
__global__ __launch_bounds__(256) void knorm(const float* __restrict__ ei,
                                             const float* __restrict__ ej,
                                             unsigned short* __restrict__ reps,
                                             float* __restrict__ pos) {
  const int r = blockIdx.x;
  const int t = threadIdx.x;
  const float4 vi = ((const float4*)(ei + (size_t)r * D))[t];
  const float4 vj = ((const float4*)(ej + (size_t)r * D))[t];
  float ssi = vi.x * vi.x + vi.y * vi.y + vi.z * vi.z + vi.w * vi.w;
  float ssj = vj.x * vj.x + vj.y * vj.y + vj.z * vj.z + vj.w * vj.w;
  float sij = vi.x * vj.x + vi.y * vj.y + vi.z * vj.z + vi.w * vj.w;
#pragma unroll
  for (int o = 32; o > 0; o >>= 1) {
    ssi += __shfl_xor(ssi, o);
    ssj += __shfl_xor(ssj, o);
    sij += __shfl_xor(sij, o);
  }
  __shared__ float red[12];
  const int lane = t & 63, wid = t >> 6;
  if (lane == 0) { red[wid * 3] = ssi; red[wid * 3 + 1] = ssj; red[wid * 3 + 2] = sij; }
  __syncthreads();
  ssi = red[0] + red[3] + red[6] + red[9];
  ssj = red[1] + red[4] + red[7] + red[10];
  sij = red[2] + red[5] + red[8] + red[11];
  const float inv_i = rsqrtf(fmaxf(ssi, 1e-24f));
  const float inv_j = rsqrtf(fmaxf(ssj, 1e-24f));
  ushort4 ui, uj;
  ui.x = f2bf(vi.x * inv_i); ui.y = f2bf(vi.y * inv_i);
  ui.z = f2bf(vi.z * inv_i); ui.w = f2bf(vi.w * inv_i);
  uj.x = f2bf(vj.x * inv_j); uj.y = f2bf(vj.y * inv_j);
  uj.z = f2bf(vj.z * inv_j); uj.w = f2bf(vj.w * inv_j);
  *((ushort4*)(reps + (size_t)r * D) + t) = ui;
  *((ushort4*)(reps + (size_t)(BSZ + r) * D) + t) = uj;
  if (t == 0) pos[r] = sij * inv_i * inv_j;
}

// ======================= shared asm helpers =======================
#define BARRIER() do { __builtin_amdgcn_s_barrier(); asm volatile("" ::: "memory"); } while (0)
#define STR2(x) #x
#define WAITV(n) asm volatile("s_waitcnt vmcnt(" STR2(n) ")" ::: "memory")
#define LGKM0() asm volatile("s_waitcnt lgkmcnt(0)" ::: "memory")

// ---------------- Kernel B: 256x256 tiles (512 = 2 clean rounds), m201-style phases -----
// 8 waves (2M x 4N); wave tile = rows {wr*64..+63}U{128+wr*64..+63},
//                    cols {wc*32..+31}U{128+wc*32..+31}  (interleaved halves).
// Per K-tile (BK=64): 4 phases, each {reads -> 2 stage gloads -> vmcnt(4) -> barrier
//   -> lgkmcnt(0) -> 16 MFMA (setprio) -> barrier}.  Stage X(t+1) half-chunks in the
//   exact order consumed: A-lo@ph1, B-lo@ph2, B-hi@ph3, A-hi@ph4; uniform vmcnt(4)
//   retires each half exactly one phase before its consumer reads (ledger in notes).
#define SG_A(ii, ktv, dst) gload16(reps + (arow0 + (ii) * 64 + srow8) * D + (ktv) * 64 + schunk * 8, \
                                   (dst) + (size_t)((ii) * 64 + w * 8) * 64)
#define SG_B(ii, ktv, dst) gload16(reps + (brow0 + (ii) * 64 + srow8) * D + (ktv) * 64 + schunk * 8, \
                                   (dst) + (size_t)((ii) * 64 + w * 8) * 64)

#define PH_A_READS(buf, Ah)                                             \
  _Pragma("unroll") for (int mm = 0; mm < 4; mm++) {                    \
    const char* rp_ = (buf) + ((Ah) * 128 + arow + mm * 16) * 128;      \
    afr[mm][0] = *(const bf16x8*)(rp_ + offk0);                         \
    afr[mm][1] = *(const bf16x8*)(rp_ + offk1);                         \
  }

#define PH_B_READS(buf, Bh, dst)                                        \
  _Pragma("unroll") for (int nn = 0; nn < 2; nn++) {                    \
    const char* rp_ = (buf) + ((Bh) * 128 + brow + nn * 16) * 128;      \
    dst[nn][0] = *(const bf16x8*)(rp_ + offk0);                         \
    dst[nn][1] = *(const bf16x8*)(rp_ + offk1);                         \
  }

#define MFMA_C(Ah, Bh, bfx)                                             \
  __builtin_amdgcn_s_setprio(1);                                        \
  _Pragma("unroll") for (int kk = 0; kk < 2; kk++)                      \
  _Pragma("unroll") for (int mm = 0; mm < 4; mm++)                      \
  _Pragma("unroll") for (int nn = 0; nn < 2; nn++)                      \
    acc[(Ah) * 4 + mm][(Bh) * 2 + nn] = __builtin_amdgcn_mfma_f32_16x16x32_bf16( \
        afr[mm][kk], bfx[nn][kk], acc[(Ah) * 4 + mm][(Bh) * 2 + nn], 0, 0, 0); \
  __builtin_amdgcn_s_setprio(0);

#define DO_TILE(ktv, STG, H1, W1, H2, W2, H3, H4)                       \
  {                                                                     \
    const int cur = (ktv) & 1;                                          \
    const char* bA = cur ? (const char*)lA1 : (const char*)lA0;         \
    const char* bB = cur ? (const char*)lB1 : (const char*)lB0;         \
    short* sA = cur ? lA0 : lA1;                                        \
    short* sB = cur ? lB0 : lB1;                                        \
    /* ph1: quadrant (A-lo, B-lo) */                                    \
    PH_A_READS(bA, 0);                                                  \
    PH_B_READS(bB, 0, bfr0);                                            \
    if (STG) { SG_A(0, (ktv) + 1, sA); SG_A(1, (ktv) + 1, sA); }        \
    if (H1) { WAITV(W1); }                                              \
    BARRIER(); LGKM0();                                                 \
    MFMA_C(0, 0, bfr0);                                                 \
    BARRIER();                                                          \
    /* ph2: quadrant (A-lo, B-hi) */                                    \
    PH_B_READS(bB, 1, bfr1);                                            \
    if (STG) { SG_B(0, (ktv) + 1, sB); SG_B(1, (ktv) + 1, sB); }        \
    if (H2) { WAITV(W2); }                                              \
    BARRIER(); LGKM0();                                                 \
    MFMA_C(0, 1, bfr1);                                                 \
    BARRIER();                                                          \
    /* ph3: quadrant (A-hi, B-hi) */                                    \
    PH_A_READS(bA, 1);                                                  \
    if (STG) { SG_B(2, (ktv) + 1, sB); SG_B(3, (ktv) + 1, sB); }        \
    if (H3) { WAITV(4); }                                               \
    BARRIER(); LGKM0();                                                 \
    MFMA_C(1, 1, bfr1);                                                 \
    BARRIER();                                                          \
    /* ph4: quadrant (A-hi, B-lo) — no reads */                         \
    if (STG) { SG_A(2, (ktv) + 1, sA); SG_A(3, (ktv) + 1, sA); }        \
    if (H4) { WAITV(4); }                                               \
    BARRIER();                                                          \
    MFMA_C(1, 0, bfr0);                                                 \
    BARRIER();                                                          \
  }

__global__ __launch_bounds__(512, 2) void kgemm3(const short* __restrict__ reps,
                                                 float* __restrict__ partial) {
  extern __shared__ char smem[];
  short* lA0 = (short*)smem;                  // 32 KB  [256][64]
  short* lA1 = (short*)(smem + 32768);
  short* lB0 = (short*)(smem + 65536);
  short* lB1 = (short*)(smem + 98304);

  // XCD-aware swizzle (512 = 8 * 64, bijective), then decode into the
  // 512-tile list: triangle minus tiles (0, 16..31).
  int bid = (int)blockIdx.x;
  bid = (bid & 7) * 64 + (bid >> 3);
  int rb, cb;
  if (bid < 16) {
    rb = 0; cb = bid;
  } else {
    int rem = bid - 16;
    rb = 1;
    while (rem >= NTB - rb) { rem -= NTB - rb; rb++; }
    cb = rb + rem;
  }

  const int t = threadIdx.x;
  const int l = t & 63, w = t >> 6;
  const int wr = w >> 2, wc = w & 3;          // 2 x 4 wave grid

  f32x4 acc[8][4];
  const f32x4 zero4 = {0.f, 0.f, 0.f, 0.f};
#pragma unroll
  for (int m = 0; m < 8; m++)
#pragma unroll
    for (int n = 0; n < 4; n++) acc[m][n] = zero4;

  const int srow8 = w * 8 + (l >> 3);          // row within 64-row inst chunk
  const int schunk = (l & 7) ^ (l >> 3);       // pre-swizzled source 16B chunk
  const size_t arow0 = (size_t)rb * 256;
  const size_t brow0 = (size_t)cb * 256;

  const int swz = (l & 7) << 4;
  const int q16 = ((l >> 4) & 3) * 16;
  const int arow = wr * 64 + (l & 15);         // A rows: Ah*128 + arow + mm*16
  const int brow = wc * 32 + (l & 15);         // B rows: Bh*128 + brow + nn*16
  const int offk0 = (q16) ^ swz;
  const int offk1 = (64 + q16) ^ swz;

  // ---- prologue: stage tile 0 in consumption order; retire A-lo+B-lo ----
  SG_A(0, 0, lA0); SG_A(1, 0, lA0);
  SG_B(0, 0, lB0); SG_B(1, 0, lB0);
  SG_B(2, 0, lB0); SG_B(3, 0, lB0);
  SG_A(2, 0, lA0); SG_A(3, 0, lA0);
  WAITV(4);
  BARRIER();

  bf16x8 afr[4][2], bfr0[2][2], bfr1[2][2];

#pragma unroll 1
  for (int kt = 0; kt < 15; ++kt) DO_TILE(kt, 1, 1, 4, 1, 4, 1, 1)
  DO_TILE(15, 0, 1, 2, 1, 0, 0, 0)

  // -------- epilogue: exp + diag mask; row/col sums split per 128-slot --------
  float rsumL[8][4], rsumH[8][4];
  float csumL[4], csumH[4];
#pragma unroll
  for (int m = 0; m < 8; m++)
#pragma unroll
    for (int j = 0; j < 4; j++) { rsumL[m][j] = 0.f; rsumH[m][j] = 0.f; }
#pragma unroll
  for (int n = 0; n < 4; n++) { csumL[n] = 0.f; csumH[n] = 0.f; }

  const int col16 = l & 15, rgp = (l >> 4) & 3;
  const bool diag = (rb == cb);
#pragma unroll
  for (int m = 0; m < 8; m++) {
    const int rowin = (m >> 2) * 128 + wr * 64 + (m & 3) * 16 + rgp * 4;
#pragma unroll
    for (int n = 0; n < 4; n++) {
      const int colin = (n >> 1) * 128 + wc * 32 + (n & 1) * 16 + col16;
#pragma unroll
      for (int j = 0; j < 4; j++) {
        const float e = (diag && (rowin + j) == colin)
                            ? 0.f
                            : exp2f(acc[m][n][j] * EXPSCALE);
        if (n < 2) rsumL[m][j] += e; else rsumH[m][j] += e;
        if (m < 4) csumL[n] += e; else csumH[n] += e;
      }
    }
  }
#pragma unroll
  for (int m = 0; m < 8; m++)
#pragma unroll
    for (int j = 0; j < 4; j++) {
      float vL = rsumL[m][j], vH = rsumH[m][j];
      vL += __shfl_xor(vL, 1); vL += __shfl_xor(vL, 2);
      vL += __shfl_xor(vL, 4); vL += __shfl_xor(vL, 8);
      vH += __shfl_xor(vH, 1); vH += __shfl_xor(vH, 2);
      vH += __shfl_xor(vH, 4); vH += __shfl_xor(vH, 8);
      rsumL[m][j] = vL; rsumH[m][j] = vH;
    }
#pragma unroll
  for (int n = 0; n < 4; n++) {
    float vL = csumL[n], vH = csumH[n];
    vL += __shfl_xor(vL, 16); vL += __shfl_xor(vL, 32);
    vH += __shfl_xor(vH, 16); vH += __shfl_xor(vH, 32);
    csumL[n] = vL; csumH[n] = vH;
  }

  float* rSL = (float*)smem;             // [4 wc][256 rows]
  float* rSH = ((float*)smem) + 1024;    // [4 wc][256 rows]
  float* cSL = ((float*)smem) + 2048;    // [2 wr][256 cols]
  float* cSH = ((float*)smem) + 2560;    // [2 wr][256 cols]
  if (col16 == 0) {
#pragma unroll
    for (int m = 0; m < 8; m++) {
      const int rowin = (m >> 2) * 128 + wr * 64 + (m & 3) * 16 + rgp * 4;
#pragma unroll
      for (int j = 0; j < 4; j++) {
        rSL[wc * 256 + rowin + j] = rsumL[m][j];
        rSH[wc * 256 + rowin + j] = rsumH[m][j];
      }
    }
  }
  if (rgp == 0) {
#pragma unroll
    for (int n = 0; n < 4; n++) {
      const int colin = (n >> 1) * 128 + wc * 32 + (n & 1) * 16 + col16;
      cSL[wr * 256 + colin] = csumL[n];
      cSH[wr * 256 + colin] = csumH[n];
    }
  }
  __syncthreads();
  // partial layout: [64 col-blocks of 128][8192 rows]
  if (t < 256) {
    const float rs_lo = rSL[t] + rSL[256 + t] + rSL[512 + t] + rSL[768 + t];
    const float rs_hi = rSH[t] + rSH[256 + t] + rSH[512 + t] + rSH[768 + t];
    partial[(size_t)(cb * 2) * N2 + rb * 256 + t] = rs_lo;
    partial[(size_t)(cb * 2 + 1) * N2 + rb * 256 + t] = rs_hi;
    if (!diag) {
      partial[(size_t)(rb * 2) * N2 + cb * 256 + t] = cSL[t] + cSL[256 + t];
      partial[(size_t)(rb * 2 + 1) * N2 + cb * 256 + t] = cSH[t] + cSH[256 + t];
    }
  }
}

// ---------------- Kernel Bq: tail — 64 quarter-tiles (128x128) of tiles (0,16..31) ------
#define QSG_A(ii, ktv, dst) gload16(reps + (qarow0 + (ii) * 32 + qsrow) * D + (ktv) * 128 + qschk * 8, \
                                    (dst) + (size_t)((ii) * 32 + w * 4) * 128)
#define QSG_B(ii, ktv, dst) gload16(reps + (qbrow0 + (ii) * 32 + qsrow) * D + (ktv) * 128 + qschk * 8, \
                                    (dst) + (size_t)((ii) * 32 + w * 4) * 128)

#define QRD(buf, row, kk) (*(const bf16x8*)((const char*)(buf) + (row) * 256 + \
                           ((((kk) * 4 + q4) ^ ((row) & 15)) << 4)))

#define QMFMA(afx, mb)                                                  \
  __builtin_amdgcn_s_setprio(1);                                        \
  _Pragma("unroll") for (int kk = 0; kk < 4; kk++)                      \
  _Pragma("unroll") for (int m2 = 0; m2 < 2; m2++)                      \
  _Pragma("unroll") for (int n = 0; n < 2; n++)                         \
    acc[(mb) + m2][n] = __builtin_amdgcn_mfma_f32_16x16x32_bf16(        \
        afx[m2][kk], bfr[n][kk], acc[(mb) + m2][n], 0, 0, 0);           \
  __builtin_amdgcn_s_setprio(0);

#define QTILE(tv, S, R, HASW, WV)                                       \
  {                                                                     \
    const int cur = (tv) & 1;                                           \
    const char* bA  = cur ? (const char*)qA1 : (const char*)qA0;        \
    const char* bAn = cur ? (const char*)qA0 : (const char*)qA1;        \
    const char* bBn = cur ? (const char*)qB0 : (const char*)qB1;        \
    short* stA = cur ? qA0 : qA1;                                       \
    short* stB = cur ? qB0 : qB1;                                       \
    _Pragma("unroll") for (int m2 = 0; m2 < 2; m2++)                    \
      _Pragma("unroll") for (int kk = 0; kk < 4; kk++)                  \
        af23[m2][kk] = QRD(bA, qarow + (2 + m2) * 16, kk);              \
    QMFMA(af01, 0);                                                     \
    BARRIER();                                                          \
    if (S) { QSG_A(0, (tv) + 2, stA); QSG_A(1, (tv) + 2, stA);          \
             QSG_A(2, (tv) + 2, stA); QSG_A(3, (tv) + 2, stA); }        \
    QMFMA(af23, 2);                                                     \
    if (S) { QSG_B(0, (tv) + 2, stB); QSG_B(1, (tv) + 2, stB);          \
             QSG_B(2, (tv) + 2, stB); QSG_B(3, (tv) + 2, stB); }        \
    if (HASW) { WAITV(WV); }                                            \
    BARRIER();                                                          \
    if (R) {                                                            \
      _Pragma("unroll") for (int m2 = 0; m2 < 2; m2++)                  \
        _Pragma("unroll") for (int kk = 0; kk < 4; kk++)                \
          af01[m2][kk] = QRD(bAn, qarow + m2 * 16, kk);                 \
      _Pragma("unroll") for (int n = 0; n < 2; n++)                     \
        _Pragma("unroll") for (int kk = 0; kk < 4; kk++)                \
          bfr[n][kk] = QRD(bBn, qbrow + n * 16, kk);                    \
    }                                                                   \
  }

__global__ __launch_bounds__(512) void kgemmq(const short* __restrict__ reps,
                                              float* __restrict__ partial) {
  extern __shared__ char smem[];
  short* qA0 = (short*)smem;                  // 32 KB [128][128]
  short* qA1 = (short*)(smem + 32768);
  short* qB0 = (short*)(smem + 65536);
  short* qB1 = (short*)(smem + 98304);

  const int bq = (int)blockIdx.x;             // 0..63
  const int s = bq >> 2, quad = bq & 3;
  const int qr = quad >> 1, qc = quad & 1;
  const int cbt = 16 + s;

  const int t = threadIdx.x;
  const int l = t & 63, w = t >> 6;
  const int wr = w >> 2, wc = w & 3;

  f32x4 acc[4][2];
  const f32x4 zero4 = {0.f, 0.f, 0.f, 0.f};
#pragma unroll
  for (int m = 0; m < 4; m++)
#pragma unroll
    for (int n = 0; n < 2; n++) acc[m][n] = zero4;

  const int qsrow = w * 4 + (l >> 4);          // row within 32-row inst chunk
  const int qschk = (l & 15) ^ (qsrow & 15);   // pre-swizzled source chunk
  const size_t qarow0 = (size_t)qr * 128;
  const size_t qbrow0 = (size_t)cbt * 256 + (size_t)qc * 128;

  const int q4 = (l >> 4) & 3;
  const int qarow = wr * 64 + (l & 15);
  const int qbrow = wc * 32 + (l & 15);

  QSG_A(0, 0, qA0); QSG_A(1, 0, qA0); QSG_A(2, 0, qA0); QSG_A(3, 0, qA0);
  QSG_B(0, 0, qB0); QSG_B(1, 0, qB0); QSG_B(2, 0, qB0); QSG_B(3, 0, qB0);
  QSG_A(0, 1, qA1); QSG_A(1, 1, qA1); QSG_A(2, 1, qA1); QSG_A(3, 1, qA1);
  QSG_B(0, 1, qB1); QSG_B(1, 1, qB1); QSG_B(2, 1, qB1); QSG_B(3, 1, qB1);
  WAITV(8);
  BARRIER();

  bf16x8 af01[2][4], af23[2][4], bfr[2][4];
#pragma unroll
  for (int m2 = 0; m2 < 2; m2++)
#pragma unroll
    for (int kk = 0; kk < 4; kk++)
      af01[m2][kk] = QRD((const char*)qA0, qarow + m2 * 16, kk);
#pragma unroll
  for (int n = 0; n < 2; n++)
#pragma unroll
    for (int kk = 0; kk < 4; kk++)
      bfr[n][kk] = QRD((const char*)qB0, qbrow + n * 16, kk);

#pragma unroll 1
  for (int tv = 0; tv < 6; ++tv) QTILE(tv, 1, 1, 1, 8)
  QTILE(6, 0, 1, 1, 0)
  QTILE(7, 0, 0, 0, 0)

  float rsum[4][4];
  float csum[2];
#pragma unroll
  for (int m = 0; m < 4; m++)
#pragma unroll
    for (int j = 0; j < 4; j++) rsum[m][j] = 0.f;
  csum[0] = 0.f; csum[1] = 0.f;

#pragma unroll
  for (int m = 0; m < 4; m++)
#pragma unroll
    for (int n = 0; n < 2; n++)
#pragma unroll
      for (int j = 0; j < 4; j++) {
        const float e = exp2f(acc[m][n][j] * EXPSCALE);
        rsum[m][j] += e;
        csum[n] += e;
      }
#pragma unroll
  for (int m = 0; m < 4; m++)
#pragma unroll
    for (int j = 0; j < 4; j++) {
      float v = rsum[m][j];
      v += __shfl_xor(v, 1); v += __shfl_xor(v, 2);
      v += __shfl_xor(v, 4); v += __shfl_xor(v, 8);
      rsum[m][j] = v;
    }
#pragma unroll
  for (int n = 0; n < 2; n++) {
    float v = csum[n];
    v += __shfl_xor(v, 16); v += __shfl_xor(v, 32);
    csum[n] = v;
  }

  const int col16 = l & 15, rgp = (l >> 4) & 3;
  float* rS = (float*)smem;            // [4 wc][128 rows]
  float* cS = ((float*)smem) + 512;    // [2 wr][128 cols]
  if (col16 == 0) {
#pragma unroll
    for (int m = 0; m < 4; m++)
#pragma unroll
      for (int j = 0; j < 4; j++)
        rS[wc * 128 + wr * 64 + m * 16 + rgp * 4 + j] = rsum[m][j];
  }
  if (rgp == 0) {
#pragma unroll
    for (int n = 0; n < 2; n++)
      cS[wr * 128 + wc * 32 + n * 16 + col16] = csum[n];
  }
  __syncthreads();
  if (t < 128) {
    const float rs = rS[t] + rS[128 + t] + rS[256 + t] + rS[384 + t];
    partial[(size_t)(cbt * 2 + qc) * N2 + qr * 128 + t] = rs;
    const float cs = cS[t] + cS[128 + t];
    partial[(size_t)qr * N2 + cbt * 256 + qc * 128 + t] = cs;
  }
}

// ---------------- Kernel C1: per-row denom = sum of 64 partials; log; block sum -----------
__device__ inline float blockReduce(float v, float* sred) {
#pragma unroll
  for (int o = 32; o > 0; o >>= 1) v += __shfl_xor(v, o);
  const int lane = threadIdx.x & 63, wid = threadIdx.x >> 6;
  if (lane == 0) sred[wid] = v;
  __syncthreads();
  v = sred[0] + sred[1] + sred[2] + sred[3];
  __syncthreads();
  return v;
}

__global__ __launch_bounds__(256) void kred1(const float* __restrict__ partial,
                                             float* __restrict__ bsum) {
  const int r = blockIdx.x * 256 + threadIdx.x;
  float d = 0.f;
#pragma unroll 8
  for (int cbx = 0; cbx < 64; ++cbx) d += partial[(size_t)cbx * N2 + r];
  float v = logf(d);
  __shared__ float sred[4];
  v = blockReduce(v, sred);
  if (threadIdx.x == 0) bsum[blockIdx.x] = v;
}

// ---------------- Kernel C2: final scalar -------------------------------------------------
__global__ __launch_bounds__(256) void kred2(const float* __restrict__ bsum,
                                             const float* __restrict__ pos,
                                             float* __restrict__ out) {
  const int t = threadIdx.x;
  float v = (t < 32) ? bsum[t] : 0.f;
  float p = 0.f;
  for (int k = t; k < BSZ; k += 256) p += pos[k];
  __shared__ float sred[4];
  v = blockReduce(v, sred);
  p = blockReduce(p, sred);
  if (t == 0) out[0] = (v - 2.0f * p / TEMPV) / (float)N2;
}

extern "C" void kernel_launch(void* const* d_in, const int* in_sizes, int n_in,
                              void* d_out, int out_size, void* d_ws, size_t ws_size,
                              hipStream_t stream) {
  const float* ei = (const float*)d_in[0];
  const float* ej = (const float*)d_in[1];
  char* ws = (char*)d_ws;
  unsigned short* reps = (unsigned short*)ws;                       // 16 MB bf16 [8192][1024]
  float* partial = (float*)(ws + (size_t)16 * 1024 * 1024);         // 2 MB  [64][8192]
  float* pos = (float*)(ws + (size_t)18 * 1024 * 1024);             // 16 KB [4096]
  float* bsum = (float*)(ws + (size_t)18 * 1024 * 1024 + 16384);    // 128 B [32]

  (void)hipFuncSetAttribute((const void*)kgemm3,
                            hipFuncAttributeMaxDynamicSharedMemorySize, 131072);
  (void)hipFuncSetAttribute((const void*)kgemmq,
                            hipFuncAttributeMaxDynamicSharedMemorySize, 131072);

  knorm<<<BSZ, 256, 0, stream>>>(ei, ej, reps, pos);
  kgemm3<<<512, 512, 131072, stream>>>((const short*)reps, partial);
  kgemmq<<<64, 512, 131072, stream>>>((const short*)reps, partial);
  kred1<<<32, 256, 0, stream>>>(partial, bsum);
  kred2<<<1, 256, 0, stream>>>(bsum, pos, (float*)d_out);
}

// Round 7
// 98.315 us; speedup vs baseline: 1.1193x; 1.1193x over previous
//
#include <hip/hip_runtime.h>

#define BSZ 4096
#define D 1024
#define N2 8192
#define TEMPV 0.5f
// exp(x/T) = exp2(x * log2(e)/T)
#define EXPSCALE 2.8853900817779268f
#define NTB 32      // 8192 / 256 tiles per dim

typedef __attribute__((ext_vector_type(8))) short bf16x8;
typedef __attribute__((ext_vector_type(4))) float f32x4;

__device__ inline unsigned short f2bf(float x) {
  unsigned int u = __float_as_uint(x);
  u += 0x7fffu + ((u >> 16) & 1u);   // round-to-nearest-even
  return (unsigned short)(u >> 16);
}

__device__ inline void gload16(const void* g, void* l) {
  __builtin_amdgcn_global_load_lds(
      (const __attribute__((address_space(1))) void*)g,
      (__attribute__((address_space(3))) void*)l, 16, 0, 0);
}

// ---------------- Kernel A: L2-normalize rows, emit bf16 reps + pos dot ----------------
__global__ __launch_bounds__(256) void knorm(const float* __restrict__ ei,
                                             const float* __restrict__ ej,
                                             unsigned short* __restrict__ reps,
                                             float* __restrict__ pos) {
  const int r = blockIdx.x;
  const int t = threadIdx.x;
  const float4 vi = ((const float4*)(ei + (size_t)r * D))[t];
  const float4 vj = ((const float4*)(ej + (size_t)r * D))[t];
  float ssi = vi.x * vi.x + vi.y * vi.y + vi.z * vi.z + vi.w * vi.w;
  float ssj = vj.x * vj.x + vj.y * vj.y + vj.z * vj.z + vj.w * vj.w;
  float sij = vi.x * vj.x + vi.y * vj.y + vi.z * vj.z + vi.w * vj.w;
#pragma unroll
  for (int o = 32; o > 0; o >>= 1) {
    ssi += __shfl_xor(ssi, o);
    ssj += __shfl_xor(ssj, o);
    sij += __shfl_xor(sij, o);
  }
  __shared__ float red[12];
  const int lane = t & 63, wid = t >> 6;
  if (lane == 0) { red[wid * 3] = ssi; red[wid * 3 + 1] = ssj; red[wid * 3 + 2] = sij; }
  __syncthreads();
  ssi = red[0] + red[3] + red[6] + red[9];
  ssj = red[1] + red[4] + red[7] + red[10];
  sij = red[2] + red[5] + red[8] + red[11];
  const float inv_i = rsqrtf(fmaxf(ssi, 1e-24f));
  const float inv_j = rsqrtf(fmaxf(ssj, 1e-24f));
  ushort4 ui, uj;
  ui.x = f2bf(vi.x * inv_i); ui.y = f2bf(vi.y * inv_i);
  ui.z = f2bf(vi.z * inv_i); ui.w = f2bf(vi.w * inv_i);
  uj.x = f2bf(vj.x * inv_j); uj.y = f2bf(vj.y * inv_j);
  uj.z = f2bf(vj.z * inv_j); uj.w = f2bf(vj.w * inv_j);
  *((ushort4*)(reps + (size_t)r * D) + t) = ui;
  *((ushort4*)(reps + (size_t)(BSZ + r) * D) + t) = uj;
  if (t == 0) pos[r] = sij * inv_i * inv_j;
}

// ======================= shared asm helpers =======================
#define BARRIER() do { __builtin_amdgcn_s_barrier(); asm volatile("" ::: "memory"); } while (0)
#define STR2(x) #x
#define WAITV(n) asm volatile("s_waitcnt vmcnt(" STR2(n) ")" ::: "memory")
#define LGKM0() asm volatile("s_waitcnt lgkmcnt(0)" ::: "memory")

// ---------------- Kernel B: 256x256 tiles (512 = 2 clean rounds), R5 engine -------------
// 8 waves (2M x 4N), wave tile 128x64, BK=64, 128 KiB LDS (A dbuf + B dbuf).
#define SG_A(ii, ktv, dst) gload16(reps + (arow0 + (ii) * 64 + srow8) * D + (ktv) * 64 + schunk * 8, \
                                   (dst) + (size_t)((ii) * 64 + w * 8) * 64)
#define SG_B(ii, ktv, dst) gload16(reps + (brow0 + (ii) * 64 + srow8) * D + (ktv) * 64 + schunk * 8, \
                                   (dst) + (size_t)((ii) * 64 + w * 8) * 64)

#define READ_AQ(buf, q) do {                                            \
    const char* rp0_ = (buf) + (arow + (2 * (q)) * 16) * 128;           \
    const char* rp1_ = (buf) + (arow + (2 * (q) + 1) * 16) * 128;       \
    af[0][0] = *(const bf16x8*)(rp0_ + offk0);                          \
    af[0][1] = *(const bf16x8*)(rp0_ + offk1);                          \
    af[1][0] = *(const bf16x8*)(rp1_ + offk0);                          \
    af[1][1] = *(const bf16x8*)(rp1_ + offk1);                          \
  } while (0)

#define READ_B2(buf, n) do {                                            \
    const char* rp_ = (buf) + (brow + (n) * 16) * 128;                  \
    bfr[n][0] = *(const bf16x8*)(rp_ + offk0);                          \
    bfr[n][1] = *(const bf16x8*)(rp_ + offk1);                          \
  } while (0)

// 16 MFMA; bfr[0..1] half first so ph1's fresh bfr[2..3] reads have cover.
#define MFMA_Q(q)                                                       \
  __builtin_amdgcn_s_setprio(1);                                        \
  _Pragma("unroll") for (int nh = 0; nh < 2; nh++)                      \
  _Pragma("unroll") for (int kk = 0; kk < 2; kk++)                      \
  _Pragma("unroll") for (int m2 = 0; m2 < 2; m2++)                      \
  _Pragma("unroll") for (int nn = 0; nn < 2; nn++) {                    \
    const int n_ = nh * 2 + nn;                                         \
    acc[2 * (q) + m2][n_] = __builtin_amdgcn_mfma_f32_16x16x32_bf16(    \
        af[m2][kk], bfr[n_][kk], acc[2 * (q) + m2][n_], 0, 0, 0);       \
  }                                                                     \
  __builtin_amdgcn_s_setprio(0);

#define DO_TILE(ktv, SA, SB, RDN, HASW, WV)                             \
  {                                                                     \
    const int cur = (ktv) & 1;                                          \
    const char* bA  = cur ? (const char*)lA1 : (const char*)lA0;        \
    const char* bB  = cur ? (const char*)lB1 : (const char*)lB0;        \
    const char* bAn = cur ? (const char*)lA0 : (const char*)lA1;        \
    const char* bBn = cur ? (const char*)lB0 : (const char*)lB1;        \
    short* stA = cur ? lA0 : lA1;                                       \
    short* stB = cur ? lB1 : lB0;                                       \
    /* ph1: q0 MFMA (ops from prev ph4); read bfr[2..3](t) + Aq1; stage A(t+1) */ \
    READ_B2(bB, 2); READ_B2(bB, 3);                                     \
    MFMA_Q(0);                                                          \
    READ_AQ(bA, 1);                                                     \
    if (SA) { SG_A(0, (ktv) + 1, stA); SG_A(1, (ktv) + 1, stA);         \
              SG_A(2, (ktv) + 1, stA); SG_A(3, (ktv) + 1, stA); }       \
    BARRIER();                                                          \
    /* ph2 */                                                           \
    MFMA_Q(1);                                                          \
    READ_AQ(bA, 2);                                                     \
    BARRIER();                                                          \
    /* ph3: stage B(t+2); counted wait */                               \
    MFMA_Q(2);                                                          \
    READ_AQ(bA, 3);                                                     \
    if (SB) { SG_B(0, (ktv) + 2, stB); SG_B(1, (ktv) + 2, stB);         \
              SG_B(2, (ktv) + 2, stB); SG_B(3, (ktv) + 2, stB); }       \
    if (HASW) { WAITV(WV); }                                            \
    BARRIER();                                                          \
    /* ph4: read next tile's Aq0 + bfr[0..1] */                         \
    MFMA_Q(3);                                                          \
    if (RDN) { READ_AQ(bAn, 0); READ_B2(bBn, 0); READ_B2(bBn, 1); }     \
    BARRIER();                                                          \
  }

__global__ __launch_bounds__(512, 2) void kgemm3(const short* __restrict__ reps,
                                                 float* __restrict__ partial) {
  extern __shared__ char smem[];
  short* lA0 = (short*)smem;                  // 32 KB  [256][64]
  short* lA1 = (short*)(smem + 32768);
  short* lB0 = (short*)(smem + 65536);
  short* lB1 = (short*)(smem + 98304);

  // XCD-aware swizzle (512 = 8 * 64, bijective), then decode into the
  // 512-tile list: triangle minus tiles (0, 16..31).
  int bid = (int)blockIdx.x;
  bid = (bid & 7) * 64 + (bid >> 3);
  int rb, cb;
  if (bid < 16) {
    rb = 0; cb = bid;
  } else {
    int rem = bid - 16;
    rb = 1;
    while (rem >= NTB - rb) { rem -= NTB - rb; rb++; }
    cb = rb + rem;
  }

  const int t = threadIdx.x;
  const int l = t & 63, w = t >> 6;
  const int wr = w >> 2, wc = w & 3;          // 2 x 4 wave grid

  f32x4 acc[8][4];
  const f32x4 zero4 = {0.f, 0.f, 0.f, 0.f};
#pragma unroll
  for (int m = 0; m < 8; m++)
#pragma unroll
    for (int n = 0; n < 4; n++) acc[m][n] = zero4;

  const int srow8 = w * 8 + (l >> 3);          // row within 64-row inst chunk
  const int schunk = (l & 7) ^ (l >> 3);       // pre-swizzled source 16B chunk
  const size_t arow0 = (size_t)rb * 256;
  const size_t brow0 = (size_t)cb * 256;

  const int swz = (l & 7) << 4;
  const int q16 = ((l >> 4) & 3) * 16;
  const int arow = wr * 128 + (l & 15);
  const int brow = wc * 64 + (l & 15);
  const int offk0 = (q16) ^ swz;
  const int offk1 = (64 + q16) ^ swz;

  // ---- prologue: B(0), A(0), B(1); wait first 8; preload regs for tile 0 ph1 ----
  SG_B(0, 0, lB0); SG_B(1, 0, lB0); SG_B(2, 0, lB0); SG_B(3, 0, lB0);
  SG_A(0, 0, lA0); SG_A(1, 0, lA0); SG_A(2, 0, lA0); SG_A(3, 0, lA0);
  SG_B(0, 1, lB1); SG_B(1, 1, lB1); SG_B(2, 1, lB1); SG_B(3, 1, lB1);
  WAITV(4);
  BARRIER();

  bf16x8 af[2][2], bfr[4][2];
  READ_AQ((const char*)lA0, 0);
  READ_B2((const char*)lB0, 0);
  READ_B2((const char*)lB0, 1);

#pragma unroll 1
  for (int kt = 0; kt < 14; ++kt) DO_TILE(kt, 1, 1, 1, 1, 4)
  DO_TILE(14, 1, 0, 1, 1, 0)
  DO_TILE(15, 0, 0, 0, 0, 0)

  // -------- epilogue: exp + diagonal mask + row/col partial sums --------
  float rsum[8][4];
  float csum[4];
#pragma unroll
  for (int m = 0; m < 8; m++)
#pragma unroll
    for (int j = 0; j < 4; j++) rsum[m][j] = 0.f;
#pragma unroll
  for (int n = 0; n < 4; n++) csum[n] = 0.f;

  const int col16 = l & 15, rgp = (l >> 4) & 3;
  const bool diag = (rb == cb);
  const int growbase = wr * 128 + rgp * 4;
  const int gcolbase = wc * 64 + col16;
#pragma unroll
  for (int m = 0; m < 8; m++) {
#pragma unroll
    for (int n = 0; n < 4; n++) {
#pragma unroll
      for (int j = 0; j < 4; j++) {
        const float e = (diag && (growbase + m * 16 + j) == (gcolbase + n * 16))
                            ? 0.f
                            : exp2f(acc[m][n][j] * EXPSCALE);
        rsum[m][j] += e;
        csum[n] += e;
      }
    }
  }
#pragma unroll
  for (int m = 0; m < 8; m++)
#pragma unroll
    for (int j = 0; j < 4; j++) {
      float v = rsum[m][j];
      v += __shfl_xor(v, 1); v += __shfl_xor(v, 2);
      v += __shfl_xor(v, 4); v += __shfl_xor(v, 8);
      rsum[m][j] = v;
    }
#pragma unroll
  for (int n = 0; n < 4; n++) {
    float v = csum[n];
    v += __shfl_xor(v, 16); v += __shfl_xor(v, 32);
    csum[n] = v;
  }

  float* rS = (float*)smem;            // [4 wc][256 rows]
  float* cS = ((float*)smem) + 1024;   // [2 wr][256 cols]
  if (col16 == 0) {
#pragma unroll
    for (int m = 0; m < 8; m++)
#pragma unroll
      for (int j = 0; j < 4; j++)
        rS[wc * 256 + wr * 128 + m * 16 + rgp * 4 + j] = rsum[m][j];
  }
  if (rgp == 0) {
#pragma unroll
    for (int n = 0; n < 4; n++)
      cS[wr * 256 + wc * 64 + n * 16 + col16] = csum[n];
  }
  __syncthreads();
  // partial layout: [68 col-blocks of 128][8192 rows]
  if (t < 256) {
    const float rs_lo = rS[t] + rS[256 + t];
    const float rs_hi = rS[512 + t] + rS[768 + t];
    partial[(size_t)(cb * 2) * N2 + rb * 256 + t] = rs_lo;
    partial[(size_t)(cb * 2 + 1) * N2 + rb * 256 + t] = rs_hi;
    if (!diag) {
      partial[(size_t)(rb * 2) * N2 + cb * 256 + t] = cS[t];
      partial[(size_t)(rb * 2 + 1) * N2 + cb * 256 + t] = cS[256 + t];
    }
  }
}

// ---------------- Kernel Bt: tail — 128 eighth-tiles (64x128) of tiles (0,16..31) -------
// 8 waves (2M x 4N), wave tile 32x32, BK=128, 8 K-iters, 96 KiB LDS,
// prefetch distance 2 with correct parity + lgkm-drained buffer turnover.
#define TSG_A(ii, ktv, dst) gload16(reps + (tarow0 + (ii) * 32 + tsrow) * D + (ktv) * 128 + tschk * 8, \
                                    (dst) + (size_t)((ii) * 32 + w * 4) * 128)
#define TSG_B(ii, ktv, dst) gload16(reps + (tbrow0 + (ii) * 32 + tsrow) * D + (ktv) * 128 + tschk * 8, \
                                    (dst) + (size_t)((ii) * 32 + w * 4) * 128)

#define TRD(buf, row, kk) (*(const bf16x8*)((const char*)(buf) + (row) * 256 + \
                           ((((kk) * 4 + q4) ^ ((row) & 15)) << 4)))

#define TMFMA(kk)                                                       \
  __builtin_amdgcn_s_setprio(1);                                        \
  _Pragma("unroll") for (int m2 = 0; m2 < 2; m2++)                      \
  _Pragma("unroll") for (int n = 0; n < 2; n++)                         \
    acc[m2][n] = __builtin_amdgcn_mfma_f32_16x16x32_bf16(               \
        af[m2][kk], bf[n][kk], acc[m2][n], 0, 0, 0);                    \
  __builtin_amdgcn_s_setprio(0);

#define TTILE(tv, S, R, HASW, WV)                                       \
  {                                                                     \
    const int cur = (tv) & 1;                                           \
    const char* bA  = cur ? (const char*)tA1 : (const char*)tA0;        \
    const char* bB  = cur ? (const char*)tB1 : (const char*)tB0;        \
    const char* bAn = cur ? (const char*)tA0 : (const char*)tA1;        \
    const char* bBn = cur ? (const char*)tB0 : (const char*)tB1;        \
    short* stA = cur ? tA1 : tA0;   /* = bA buffer: parity(t+2) */      \
    short* stB = cur ? tB1 : tB0;                                       \
    /* ph1: read k-slices 2,3 of tile tv; MFMA k-slices 0,1 */          \
    _Pragma("unroll") for (int kk = 2; kk < 4; kk++) {                  \
      _Pragma("unroll") for (int m2 = 0; m2 < 2; m2++)                  \
        af[m2][kk] = TRD(bA, tarow_r + m2 * 16, kk);                    \
      _Pragma("unroll") for (int n = 0; n < 2; n++)                     \
        bf[n][kk] = TRD(bB, tbrow_r + n * 16, kk);                      \
    }                                                                   \
    TMFMA(0); TMFMA(1);                                                 \
    LGKM0();                                                            \
    BARRIER();                                                          \
    /* ph2: stage tile tv+2 into bA/bB buffers; MFMA k-slices 2,3 */    \
    if (S) { TSG_A(0, (tv) + 2, stA); TSG_A(1, (tv) + 2, stA);          \
             TSG_B(0, (tv) + 2, stB); TSG_B(1, (tv) + 2, stB);          \
             TSG_B(2, (tv) + 2, stB); TSG_B(3, (tv) + 2, stB); }        \
    TMFMA(2); TMFMA(3);                                                 \
    if (HASW) { WAITV(WV); }                                            \
    BARRIER();                                                          \
    /* R: read tile tv+1 k-slices 0,1 */                                \
    if (R) {                                                            \
      _Pragma("unroll") for (int kk = 0; kk < 2; kk++) {                \
        _Pragma("unroll") for (int m2 = 0; m2 < 2; m2++)                \
          af[m2][kk] = TRD(bAn, tarow_r + m2 * 16, kk);                 \
        _Pragma("unroll") for (int n = 0; n < 2; n++)                   \
          bf[n][kk] = TRD(bBn, tbrow_r + n * 16, kk);                   \
      }                                                                 \
    }                                                                   \
  }

__global__ __launch_bounds__(512) void kgemmt(const short* __restrict__ reps,
                                              float* __restrict__ partial) {
  extern __shared__ char smem[];
  short* tA0 = (short*)smem;                  // 16 KB [64][128]
  short* tA1 = (short*)(smem + 16384);
  short* tB0 = (short*)(smem + 32768);        // 32 KB [128][128]
  short* tB1 = (short*)(smem + 65536);

  const int b = (int)blockIdx.x;              // 0..127
  const int s = b >> 3, sub = b & 7;
  const int qr = sub >> 1;                    // 64-row chunk of rows 0..255
  const int qc = sub & 1;                     // 128-col half of the 256-col tile
  const int cbt = 16 + s;

  const int t = threadIdx.x;
  const int l = t & 63, w = t >> 6;
  const int wr = w >> 2, wc = w & 3;          // 2 x 4 wave grid

  f32x4 acc[2][2];
  const f32x4 zero4 = {0.f, 0.f, 0.f, 0.f};
#pragma unroll
  for (int m = 0; m < 2; m++)
#pragma unroll
    for (int n = 0; n < 2; n++) acc[m][n] = zero4;

  // staging: inst = 512 lanes x 16B = 32 rows x 256B
  const int tsrow = w * 4 + (l >> 4);          // row within 32-row inst chunk
  const int tschk = (l & 15) ^ (tsrow & 15);   // pre-swizzled source 16B chunk
  const size_t tarow0 = (size_t)qr * 64;
  const size_t tbrow0 = (size_t)cbt * 256 + (size_t)qc * 128;

  // read side
  const int q4 = (l >> 4) & 3;
  const int tarow_r = wr * 32 + (l & 15);
  const int tbrow_r = wc * 32 + (l & 15);

  // ---- prologue: stage tiles 0,1; retire tile 0; preload k-slices 0,1 ----
  TSG_A(0, 0, tA0); TSG_A(1, 0, tA0);
  TSG_B(0, 0, tB0); TSG_B(1, 0, tB0); TSG_B(2, 0, tB0); TSG_B(3, 0, tB0);
  TSG_A(0, 1, tA1); TSG_A(1, 1, tA1);
  TSG_B(0, 1, tB1); TSG_B(1, 1, tB1); TSG_B(2, 1, tB1); TSG_B(3, 1, tB1);
  WAITV(6);
  BARRIER();

  bf16x8 af[2][4], bf[2][4];
#pragma unroll
  for (int kk = 0; kk < 2; kk++) {
#pragma unroll
    for (int m2 = 0; m2 < 2; m2++) af[m2][kk] = TRD((const char*)tA0, tarow_r + m2 * 16, kk);
#pragma unroll
    for (int n = 0; n < 2; n++) bf[n][kk] = TRD((const char*)tB0, tbrow_r + n * 16, kk);
  }

#pragma unroll 1
  for (int tv = 0; tv < 6; ++tv) TTILE(tv, 1, 1, 1, 6)
  TTILE(6, 0, 1, 1, 0)
  TTILE(7, 0, 0, 0, 0)

  // -------- epilogue (no diagonal: rows < 256, cols >= 4096) --------
  float rsum[2][4];
  float csum[2];
#pragma unroll
  for (int m = 0; m < 2; m++)
#pragma unroll
    for (int j = 0; j < 4; j++) rsum[m][j] = 0.f;
  csum[0] = 0.f; csum[1] = 0.f;

#pragma unroll
  for (int m = 0; m < 2; m++)
#pragma unroll
    for (int n = 0; n < 2; n++)
#pragma unroll
      for (int j = 0; j < 4; j++) {
        const float e = exp2f(acc[m][n][j] * EXPSCALE);
        rsum[m][j] += e;
        csum[n] += e;
      }
#pragma unroll
  for (int m = 0; m < 2; m++)
#pragma unroll
    for (int j = 0; j < 4; j++) {
      float v = rsum[m][j];
      v += __shfl_xor(v, 1); v += __shfl_xor(v, 2);
      v += __shfl_xor(v, 4); v += __shfl_xor(v, 8);
      rsum[m][j] = v;
    }
#pragma unroll
  for (int n = 0; n < 2; n++) {
    float v = csum[n];
    v += __shfl_xor(v, 16); v += __shfl_xor(v, 32);
    csum[n] = v;
  }

  const int col16 = l & 15, rgp = (l >> 4) & 3;
  float* rS = (float*)smem;            // [4 wc][64 rows]
  float* cS = ((float*)smem) + 256;    // [2 wr][128 cols]
  if (col16 == 0) {
#pragma unroll
    for (int m = 0; m < 2; m++)
#pragma unroll
      for (int j = 0; j < 4; j++)
        rS[wc * 64 + wr * 32 + m * 16 + rgp * 4 + j] = rsum[m][j];
  }
  if (rgp == 0) {
#pragma unroll
    for (int n = 0; n < 2; n++)
      cS[wr * 128 + wc * 32 + n * 16 + col16] = csum[n];
  }
  __syncthreads();
  if (t < 64) {
    const float rs = rS[t] + rS[64 + t] + rS[128 + t] + rS[192 + t];
    partial[(size_t)(cbt * 2 + qc) * N2 + qr * 64 + t] = rs;
  }
  if (t < 128) {
    const float cs = cS[t] + cS[128 + t];
    partial[(size_t)(64 + qr) * N2 + cbt * 256 + qc * 128 + t] = cs;
  }
}

// ---------------- Kernel C1: per-row denom; log; block sum --------------------------------
__device__ inline float blockReduce(float v, float* sred) {
#pragma unroll
  for (int o = 32; o > 0; o >>= 1) v += __shfl_xor(v, o);
  const int lane = threadIdx.x & 63, wid = threadIdx.x >> 6;
  if (lane == 0) sred[wid] = v;
  __syncthreads();
  v = sred[0] + sred[1] + sred[2] + sred[3];
  __syncthreads();
  return v;
}

__global__ __launch_bounds__(256) void kred1(const float* __restrict__ partial,
                                             float* __restrict__ bsum) {
  const int r = blockIdx.x * 256 + threadIdx.x;
  float d = 0.f;
#pragma unroll 8
  for (int cbx = 0; cbx < 64; ++cbx) d += partial[(size_t)cbx * N2 + r];
  if (blockIdx.x >= 16) {   // rows >= 4096: add tail colsum slots 64..67
#pragma unroll
    for (int cbx = 64; cbx < 68; ++cbx) d += partial[(size_t)cbx * N2 + r];
  }
  float v = logf(d);
  __shared__ float sred[4];
  v = blockReduce(v, sred);
  if (threadIdx.x == 0) bsum[blockIdx.x] = v;
}

// ---------------- Kernel C2: final scalar -------------------------------------------------
__global__ __launch_bounds__(256) void kred2(const float* __restrict__ bsum,
                                             const float* __restrict__ pos,
                                             float* __restrict__ out) {
  const int t = threadIdx.x;
  float v = (t < 32) ? bsum[t] : 0.f;
  float p = 0.f;
  for (int k = t; k < BSZ; k += 256) p += pos[k];
  __shared__ float sred[4];
  v = blockReduce(v, sred);
  p = blockReduce(p, sred);
  if (t == 0) out[0] = (v - 2.0f * p / TEMPV) / (float)N2;
}

extern "C" void kernel_launch(void* const* d_in, const int* in_sizes, int n_in,
                              void* d_out, int out_size, void* d_ws, size_t ws_size,
                              hipStream_t stream) {
  const float* ei = (const float*)d_in[0];
  const float* ej = (const float*)d_in[1];
  char* ws = (char*)d_ws;
  unsigned short* reps = (unsigned short*)ws;                       // 16 MB bf16 [8192][1024]
  float* partial = (float*)(ws + (size_t)16 * 1024 * 1024);         // 2.18 MB [68][8192]
  float* pos = (float*)(ws + (size_t)16 * 1024 * 1024 + 2304 * 1024);   // 16 KB [4096]
  float* bsum = (float*)(ws + (size_t)16 * 1024 * 1024 + 2304 * 1024 + 16384); // 128 B

  (void)hipFuncSetAttribute((const void*)kgemm3,
                            hipFuncAttributeMaxDynamicSharedMemorySize, 131072);
  (void)hipFuncSetAttribute((const void*)kgemmt,
                            hipFuncAttributeMaxDynamicSharedMemorySize, 98304);

  knorm<<<BSZ, 256, 0, stream>>>(ei, ej, reps, pos);
  kgemm3<<<512, 512, 131072, stream>>>((const short*)reps, partial);
  kgemmt<<<128, 512, 98304, stream>>>((const short*)reps, partial);
  kred1<<<32, 256, 0, stream>>>(partial, bsum);
  kred2<<<1, 256, 0, stream>>>(bsum, pos, (float*)d_out);
}